// Round 4
// baseline (98.412 us; speedup 1.0000x reference)
//
#include <hip/hip_runtime.h>

#define N_TEX 65536
#define C 16
#define U 4194304
#define ILP 4

typedef float    f32x4 __attribute__((ext_vector_type(4)));
typedef _Float16 f16x4 __attribute__((ext_vector_type(4)));

// ---------------------------------------------------------------------------
// Kernel 1: convert the fp32 texture (N_TEX x C = 1M floats, 4 MiB) to fp16
// (2 MiB) in d_ws. Runs every launch (deterministic), ~2 us. Cached stores on
// purpose: we WANT the fp16 texture resident in L2 for the sampler.
// ---------------------------------------------------------------------------
__global__ __launch_bounds__(256) void convert_kernel(
    const f32x4* __restrict__ in, f16x4* __restrict__ out16)
{
    const int i = blockIdx.x * 256 + threadIdx.x;   // one f32x4 -> f16x4
    f32x4 v = __builtin_nontemporal_load(&in[i]);
    f16x4 h;
    h.x = (_Float16)v.x; h.y = (_Float16)v.y;
    h.z = (_Float16)v.z; h.w = (_Float16)v.w;
    out16[i] = h;
}

// ---------------------------------------------------------------------------
// Kernel 2: sampler. 4 consecutive lanes per sample, one f16x4 (4 channels,
// 8 B) gather per row per lane. A sample's two rows (i1 = i0+1) span 64
// contiguous bytes -> 1-2 cache lines (was 2-3 with fp32). Output stores
// stay fully-coalesced fp32 (64 lanes x 16 B = 1 KiB/instr).
// ---------------------------------------------------------------------------
__global__ __launch_bounds__(256) void sampler1d_kernel(
    const f16x4* __restrict__ tex16,   // [N_TEX][4] f16x4 (16 halves per row)
    const float* __restrict__ param,   // [U]
    f32x4*       __restrict__ out)     // [U][4]
{
    const int NT  = (U * 4) / ILP;                 // total threads
    const int tid = blockIdx.x * 256 + threadIdx.x;
    const int q   = tid & 3;                       // channel quad (NT % 4 == 0)

    float p[ILP];
#pragma unroll
    for (int k = 0; k < ILP; ++k)
        p[k] = __builtin_nontemporal_load(&param[(tid + k * NT) >> 2]);

    float w[ILP];
    f16x4 a[ILP], b[ILP];
#pragma unroll
    for (int k = 0; k < ILP; ++k) {
        const float t = p[k] * (float)(N_TEX - 1);
        float f = floorf(t);
        f = fminf(fmaxf(f, 0.0f), (float)(N_TEX - 1));
        const int i0 = (int)f;
        const int i1 = min(i0 + 1, N_TEX - 1);
        w[k] = t - f;
        a[k] = tex16[i0 * 4 + q];
        b[k] = tex16[i1 * 4 + q];
    }

#pragma unroll
    for (int k = 0; k < ILP; ++k) {
        const float wk = w[k], iw = 1.0f - wk;
        f32x4 r;
        r.x = (float)a[k].x * iw + (float)b[k].x * wk;
        r.y = (float)a[k].y * iw + (float)b[k].y * wk;
        r.z = (float)a[k].z * iw + (float)b[k].z * wk;
        r.w = (float)a[k].w * iw + (float)b[k].w * wk;
        __builtin_nontemporal_store(r, &out[tid + k * NT]);
    }
}

extern "C" void kernel_launch(void* const* d_in, const int* in_sizes, int n_in,
                              void* d_out, int out_size, void* d_ws, size_t ws_size,
                              hipStream_t stream) {
    const f32x4* tex32 = (const f32x4*)d_in[0];
    const float* param = (const float*)d_in[1];
    f32x4*       out   = (f32x4*)d_out;
    f16x4*       tex16 = (f16x4*)d_ws;             // 2 MiB of scratch

    // Convert texture to fp16 (1M floats / 4 per thread = 262,144 threads).
    convert_kernel<<<(N_TEX * C / 4) / 256, 256, 0, stream>>>(tex32, tex16);

    const int total_thr = (U * 4) / ILP;
    sampler1d_kernel<<<total_thr / 256, 256, 0, stream>>>(tex16, param, out);
}